// Round 11
// baseline (119.229 us; speedup 1.0000x reference)
//
#include <hip/hip_runtime.h>
#include <math.h>

// Problem constants
#define B_  8
#define D_  128
#define L_  2048
#define H_  8
#define DH_ 16

#define LOG2E 1.4426950408889634f

typedef __bf16 bf16x8 __attribute__((ext_vector_type(8)));
typedef float  floatx4 __attribute__((ext_vector_type(4)));
typedef float  floatx16 __attribute__((ext_vector_type(16)));

#if __has_builtin(__builtin_amdgcn_exp2f)
#define EXP2(x) __builtin_amdgcn_exp2f(x)
#else
#define EXP2(x) exp2f(x)
#endif

// ---------------------------------------------------------------------------
// Weight pre-convert: fp32 W -> bf16 MFMA frag layout (lane idx = col,
// k = quad*8+j). tiles 0..7 = Q heads (W_q pre-scaled by DH^-0.5 * log2e so
// attn softmax is exp2(s)), 8..15 = K, 16..23 = V.
// ---------------------------------------------------------------------------
__global__ __launch_bounds__(256) void wconv_kernel(
    const float* __restrict__ wmem, const float* __restrict__ wq,
    __bf16* __restrict__ Wb) {
  const int tile = blockIdx.x;
  const int tid = threadIdx.x;
  const int kc = tid >> 6, lane = tid & 63;
  const int quad = lane >> 4, col = lane & 15;
  const float* src;
  float scale = 1.0f;
  if (tile < 8) {
    src = wq + (tile * 16 + col) * D_;
    scale = 0.25f * LOG2E;  // DH^-0.5 and log2e folded into W_q
  } else if (tile < 16) {
    src = wmem + ((tile - 8) * 16 + col) * D_;
  } else {
    src = wmem + (128 + (tile - 16) * 16 + col) * D_;
  }
  const float* p = src + kc * 32 + quad * 8;
  bf16x8 w;
#pragma unroll
  for (int j = 0; j < 8; ++j) w[j] = (__bf16)(p[j] * scale);
  *(bf16x8*)(Wb + ((size_t)((tile * 4 + kc) * 64) + lane) * 8) = w;
}

// ---------------------------------------------------------------------------
// Projection (round-8, unchanged): 16 l-rows/block, 4 waves x 6 tiles.
// Qs natural; Ks tau-permuted (key bits 2<->3 swapped); V^T with mask folded:
// Vp[bh][tile][row][col]: rows 0-15 = V^T*mask, row 16 = mask (l-sum row),
// rows 17-31 unwritten (harmless garbage).
// ---------------------------------------------------------------------------
__global__ __launch_bounds__(256) void proj_kernel(
    const float* __restrict__ qin, const int* __restrict__ mask,
    const __bf16* __restrict__ Wb, __bf16* __restrict__ Qs,
    __bf16* __restrict__ Ks, __bf16* __restrict__ Vp) {
  __shared__ float xl[16][132];  // row stride >= 128 (D)!
  const int b = blockIdx.x >> 7;
  const int l0 = (blockIdx.x & 127) * 16;
  const int tid = threadIdx.x;

#pragma unroll
  for (int i = 0; i < 2; ++i) {
    int idx = i * 256 + tid;
    int d = idx >> 2;
    int l4 = (idx & 3) * 4;
    const float4 v = *(const float4*)&qin[(b * D_ + d) * L_ + l0 + l4];
    xl[l4 + 0][d] = v.x;
    xl[l4 + 1][d] = v.y;
    xl[l4 + 2][d] = v.z;
    xl[l4 + 3][d] = v.w;
  }

  // Mask row 16 of each head's Vp tile for our 16 columns.
  if (tid < 128) {
    const int hh = tid >> 4, c = tid & 15;
    const float mv = (float)mask[b * L_ + l0 + c];
    __bf16* dst = Vp +
        (((size_t)(b * H_ + hh) * 64 + (l0 >> 5)) * 32 + 16) * 32 +
        (l0 & 31) + c;
    *dst = (__bf16)mv;
  }
  __syncthreads();

  const int lane = tid & 63, wave = tid >> 6;
  const int quad = lane >> 4, col = lane & 15;

  bf16x8 af[4];
#pragma unroll
  for (int kc = 0; kc < 4; ++kc) {
    const float* s = &xl[col][kc * 32 + quad * 8];
#pragma unroll
    for (int j = 0; j < 8; ++j) af[kc][j] = (__bf16)s[j];
  }

  const int lbase = l0 + quad * 4;                       // Q rows
  const int quadK = ((quad & 1) << 1) | (quad >> 1);     // tau: swap bits 2,3
  const int lbaseK = l0 + quadK * 4;                     // K rows (permuted)
  const float mvv = (float)mask[b * L_ + l0 + col];      // V column mask

#pragma unroll
  for (int tt = 0; tt < 6; ++tt) {
    const int tile = wave * 6 + tt;
    floatx4 acc = {0.f, 0.f, 0.f, 0.f};
    const bool isV = (tile >= 16);
#pragma unroll
    for (int kc = 0; kc < 4; ++kc) {
      bf16x8 wf =
          *(const bf16x8*)(Wb + ((size_t)((tile * 4 + kc) * 64) + lane) * 8);
      acc = isV ? __builtin_amdgcn_mfma_f32_16x16x32_bf16(wf, af[kc], acc, 0, 0, 0)
                : __builtin_amdgcn_mfma_f32_16x16x32_bf16(af[kc], wf, acc, 0, 0, 0);
    }
    if (tile < 8) {  // Q head
      __bf16* dst = Qs + ((size_t)((b * H_ + tile) * L_) + lbase) * DH_ + col;
#pragma unroll
      for (int r = 0; r < 4; ++r) dst[r * DH_] = (__bf16)acc[r];
    } else if (tile < 16) {  // K head, tau-permuted rows
      __bf16* dst =
          Ks + ((size_t)((b * H_ + tile - 8) * L_) + lbaseK) * DH_ + col;
#pragma unroll
      for (int r = 0; r < 4; ++r) dst[r * DH_] = (__bf16)acc[r];
    } else {  // V^T * mask
      __bf16* dst = Vp +
          (((size_t)(b * H_ + (tile - 16)) * 64 + (l0 >> 5)) * 32 + quad * 4) * 32 +
          (l0 & 31) + col;
#pragma unroll
      for (int r = 0; r < 4; ++r) dst[r * 32] = (__bf16)(acc[r] * mvv);
    }
  }
}

// ---------------------------------------------------------------------------
// Attention v9: round-10 tile body + K-SPLIT x4 within the block.
// Block = ONE 32-q tile; wave w processes K-tiles [w*16, w*16+16) into
// private accumulators (fixed-shift partials = plain sums -> exact merge),
// then a 16 KB LDS merge and wave-0 epilogue. Quadruples wave-tasks
// (16384) -> ~24 waves/CU resident, fine-grained drain.
// XCD swizzle: idx = qt*64 + bh -> idx%8 = bh%8 (K/V of one bh pinned to
// one XCD's L2; FETCH stays ~1x).
// grid = B*H*(L/32) = 4096 blocks x 256 threads.
// ---------------------------------------------------------------------------
__global__ __launch_bounds__(256, 6) void attn_kernel(
    const __bf16* __restrict__ Qs, const __bf16* __restrict__ Ks,
    const __bf16* __restrict__ Vp, float* __restrict__ out) {
  __shared__ float red[4][16][64];  // [wave][reg][lane] merge buffer
  const int idx = blockIdx.x;
  const int qt = idx >> 6;        // 64 q-tiles of 32
  const int bhi = idx & 63;       // bh minor -> idx%8 = h%8
  const int h = bhi & 7;
  const int b = bhi >> 3;
  const int tid = threadIdx.x;
  const int lane = tid & 63, wave = tid >> 6;
  const int n = lane & 31, hh = lane >> 5;
  const int q0 = qt * 32;
  const size_t bh = (size_t)(b * H_ + h);

  // Q B-frag: B[k=dh=8*hh+j][n=q]  (same for all 4 waves of the block)
  const bf16x8 qf = *(const bf16x8*)(Qs + (bh * L_ + q0 + n) * DH_ + 8 * hh);

  const __bf16* Kp = Ks + bh * L_ * DH_ + (size_t)n * DH_ + 8 * hh;
  const __bf16* Vq = Vp + (bh * 64 * 32 + (size_t)n) * 32 + 8 * hh;

  floatx16 acc0, acc1;
#pragma unroll
  for (int r = 0; r < 16; ++r) { acc0[r] = 0.f; acc1[r] = 0.f; }
  const floatx16 zz = acc0;

  auto tile = [&](int t, floatx16& acc) {
    bf16x8 kf = *(const bf16x8*)(Kp + (size_t)t * 32 * DH_);
    const __bf16* vp = Vq + (size_t)t * 1024;
    bf16x8 v0 = *(const bf16x8*)(vp);
    bf16x8 v1 = *(const bf16x8*)(vp + 16);
    floatx16 s = __builtin_amdgcn_mfma_f32_32x32x16_bf16(kf, qf, zz, 0, 0, 0);
    bf16x8 pA, pB;
#pragma unroll
    for (int j = 0; j < 8; ++j) pA[j] = (__bf16)EXP2(s[j]);
#pragma unroll
    for (int j = 0; j < 8; ++j) pB[j] = (__bf16)EXP2(s[8 + j]);
    acc = __builtin_amdgcn_mfma_f32_32x32x16_bf16(v0, pA, acc, 0, 0, 0);
    acc = __builtin_amdgcn_mfma_f32_32x32x16_bf16(v1, pB, acc, 0, 0, 0);
  };

  // This wave's 16 K-tiles (keys wave*512 .. wave*512+511)
  const int tbeg = wave * 16;
#pragma unroll 1
  for (int t = tbeg; t < tbeg + 16; t += 2) {
    tile(t, acc0);
    tile(t + 1, acc1);
  }

  // Merge partials across the 4 waves via LDS (conflict-free layout).
#pragma unroll
  for (int r = 0; r < 16; ++r) red[wave][r][lane] = acc0[r] + acc1[r];
  __syncthreads();

  if (wave == 0) {
    floatx16 acc;
#pragma unroll
    for (int r = 0; r < 16; ++r)
      acc[r] = (red[0][r][lane] + red[1][r][lane]) +
               (red[2][r][lane] + red[3][r][lane]);

    // l = row 16 of O^T = reg 8 on the hh==0 half; broadcast to hh==1.
    float lmine = acc[8];
    float lother = __shfl_xor(lmine, 32, 64);
    float inv = __builtin_amdgcn_rcpf(hh ? lother : lmine);

    // regs 0-7 = valid dh rows for this half: dh = (r&3)+8*(r>>2)+4*hh
    float* obase = out + ((size_t)(b * D_ + h * DH_)) * L_ + q0 + n;
#pragma unroll
    for (int r = 0; r < 8; ++r) {
      const int dh = (r & 3) + 8 * (r >> 2) + 4 * hh;
      obase[(size_t)dh * L_] = acc[r] * inv;
    }
  }
}

// ---------------------------------------------------------------------------
extern "C" void kernel_launch(void* const* d_in, const int* in_sizes, int n_in,
                              void* d_out, int out_size, void* d_ws,
                              size_t ws_size, hipStream_t stream) {
  const float* queries = (const float*)d_in[0];  // [B, D, L] fp32
  const int*   mask    = (const int*)d_in[1];    // [B, L] int32
  const float* wmem    = (const float*)d_in[2];  // [2D, D] fp32
  const float* wq      = (const float*)d_in[3];  // [D, D] fp32
  float* out = (float*)d_out;                    // [B, D, L] fp32

  // Workspace: Qs 4 MiB | Ks 4 MiB | Vp 8 MiB.
  const size_t SEG = (size_t)B_ * H_ * L_ * DH_ * sizeof(__bf16);
  __bf16* Qs = (__bf16*)d_ws;
  __bf16* Ks = (__bf16*)((char*)d_ws + SEG);
  __bf16* Vp = (__bf16*)((char*)d_ws + 2 * SEG);

  // Wb (96 KiB) in d_out scratch: wconv writes, proj reads, attn then
  // overwrites ALL of d_out — stream-ordered, race-free.
  __bf16* Wb = (__bf16*)((char*)d_out + (4u << 20));

  wconv_kernel<<<24, 256, 0, stream>>>(wmem, wq, Wb);
  proj_kernel<<<B_ * (L_ / 16), 256, 0, stream>>>(queries, mask, Wb, Qs, Ks, Vp);
  attn_kernel<<<B_ * H_ * (L_ / 32), 256, 0, stream>>>(Qs, Ks, Vp, out);
}